// Round 2
// baseline (703.133 us; speedup 1.0000x reference)
//
#include <hip/hip_runtime.h>
#include <math.h>

// MoE: B=2 S=2048 D=1024 E=8 H=4096 K=2
#define Bc 2
#define Sc 2048
#define Dc 1024
#define Ec 8
#define Hc 4096
#define Tc (Bc*Sc)          // 4096 tokens
#define NSLOT (Tc*2)        // 8192 token-expert slots (top-2 always)
#define FINAL_N ((size_t)Tc*Dc)
#define BK 32               // K-panel (bf16 elems) = 64B per row = 4x 16B chunks

typedef float f32x4 __attribute__((ext_vector_type(4)));
typedef __bf16 bf16x8 __attribute__((ext_vector_type(8)));

__device__ __forceinline__ unsigned short f2bf(float f) {
    union { float f; unsigned int u; } v; v.f = f;
    return (unsigned short)((v.u + 0x7fffu + ((v.u >> 16) & 1u)) >> 16);
}

// async global->LDS, 16B per lane. LDS dest = uniform base + lane*16 (linear).
__device__ __forceinline__ void gload16(const unsigned short* g, unsigned short* l) {
    __builtin_amdgcn_global_load_lds(
        (const __attribute__((address_space(1))) unsigned int*)g,
        (__attribute__((address_space(3))) unsigned int*)l,
        16, 0, 0);
}

// raw barrier with compiler fences (NO vmcnt(0) drain, unlike __syncthreads)
__device__ __forceinline__ void fence_bar() {
    __builtin_amdgcn_sched_barrier(0);
    asm volatile("s_barrier" ::: "memory");
    __builtin_amdgcn_sched_barrier(0);
}

// ---------------- x -> bf16 ----------------
__global__ void k_cvt_x(const float* __restrict__ x, unsigned short* __restrict__ xbf) {
    int gid = blockIdx.x * 256 + threadIdx.x;     // Tc*Dc/8 threads
    const float4* p = (const float4*)x + (size_t)gid * 2;
    float4 a = p[0], b = p[1];
    ushort4 r0 = { f2bf(a.x), f2bf(a.y), f2bf(a.z), f2bf(a.w) };
    ushort4 r1 = { f2bf(b.x), f2bf(b.y), f2bf(b.z), f2bf(b.w) };
    ushort4* o = (ushort4*)xbf + (size_t)gid * 2;
    o[0] = r0; o[1] = r1;
}

// ------- [R][C] fp32 -> [C][R] bf16, 64x64 tiles; z selects {matrix, expert} -------
__global__ void k_transpose_cvt2(const float* __restrict__ inA, const float* __restrict__ inB,
                                 unsigned short* __restrict__ outA, unsigned short* __restrict__ outB,
                                 int R, int C, int nz_per_mat) {
    __shared__ float tile[64][65];
    int z = blockIdx.z;
    const float* in; unsigned short* out;
    if (z < nz_per_mat) { in = inA; out = outA; }
    else { in = inB; out = outB; z -= nz_per_mat; }
    size_t base = (size_t)z * (size_t)R * C;
    int cb = blockIdx.x * 64, rb = blockIdx.y * 64;
    int t = threadIdx.x;             // 256
    int q = t & 15, g = t >> 4;
    #pragma unroll
    for (int j = 0; j < 4; j++) {
        int row = g + 16*j;
        float4 v = *(const float4*)&in[base + (size_t)(rb+row)*C + cb + q*4];
        tile[row][q*4+0] = v.x; tile[row][q*4+1] = v.y;
        tile[row][q*4+2] = v.z; tile[row][q*4+3] = v.w;
    }
    __syncthreads();
    #pragma unroll
    for (int j = 0; j < 4; j++) {
        int co = g + 16*j;
        ushort4 o;
        o.x = f2bf(tile[q*4+0][co]); o.y = f2bf(tile[q*4+1][co]);
        o.z = f2bf(tile[q*4+2][co]); o.w = f2bf(tile[q*4+3][co]);
        *(ushort4*)&out[base + (size_t)(cb+co)*R + rb + q*4] = o;
    }
}

// ---------------- gating: one wave per token ----------------
__global__ void k_gate(const float* __restrict__ x, const float* __restrict__ noise,
                       const float* __restrict__ Wg, const float* __restrict__ nw,
                       float* __restrict__ out_idx, int* __restrict__ counts,
                       int* __restrict__ tok_top, float* __restrict__ tok_w) {
    int t = blockIdx.x;
    int lane = threadIdx.x;                     // 64
    const float* xr = x + (size_t)t * Dc;
    double acc[Ec];
    #pragma unroll
    for (int e = 0; e < Ec; e++) acc[e] = 0.0;
    for (int i = 0; i < Dc/64; i++) {
        int d = lane + i*64;
        double xv = (double)xr[d];
        #pragma unroll
        for (int e = 0; e < Ec; e++) acc[e] += xv * (double)Wg[e*Dc + d];
    }
    #pragma unroll
    for (int e = 0; e < Ec; e++)
        for (int off = 32; off > 0; off >>= 1)
            acc[e] += __shfl_down(acc[e], off);
    if (lane == 0) {
        double noisy[Ec];
        #pragma unroll
        for (int e = 0; e < Ec; e++)
            noisy[e] = acc[e] + (double)noise[t*Ec + e] * (double)nw[e];
        int i0 = 0;
        for (int e = 1; e < Ec; e++) if (noisy[e] > noisy[i0]) i0 = e;   // ties -> lowest idx
        int i1 = -1;
        for (int e = 0; e < Ec; e++) {
            if (e == i0) continue;
            if (i1 < 0 || noisy[e] > noisy[i1]) i1 = e;
        }
        double ee = exp(noisy[i1] - noisy[i0]);   // v1 <= v0, stable
        float w0 = (float)(1.0 / (1.0 + ee));
        float w1 = (float)(ee / (1.0 + ee));
        out_idx[t*2 + 0] = (float)i0;
        out_idx[t*2 + 1] = (float)i1;
        tok_top[t*2] = i0; tok_top[t*2+1] = i1;
        tok_w[t*2] = w0;   tok_w[t*2+1] = w1;
        atomicAdd(&counts[i0], 1);
        atomicAdd(&counts[i1], 1);
    }
}

__global__ void k_scan(const int* __restrict__ counts, int* __restrict__ offsets) {
    if (threadIdx.x == 0) {
        int s = 0;
        for (int e = 0; e < Ec; e++) { offsets[e] = s; s += counts[e]; }
        offsets[Ec] = s;
    }
}

__global__ void k_fill(const int* __restrict__ tok_top, const int* __restrict__ offsets,
                       int* __restrict__ fill, int* __restrict__ slot_token,
                       int* __restrict__ slot_of) {
    int t = blockIdx.x * 256 + threadIdx.x;
    if (t >= Tc) return;
    #pragma unroll
    for (int j = 0; j < 2; j++) {
        int e = tok_top[t*2 + j];
        int pos = atomicAdd(&fill[e], 1);
        int slot = offsets[e] + pos;
        slot_token[slot] = t;
        slot_of[t*2 + j] = slot;
    }
}

// ---------------- GEMM1: HH = (X@W1+b1) * silu(X@W2+b2), per expert ----------------
// 256x128 tile, BK=32, 8 waves (4Mx2N), 64x64/wave/matrix.
// 3-slot LDS ring, register prefetch of next-iter fragments INSIDE the MFMA region
// (ds_read ∥ MFMA overlap at CU level), ONE barrier per iteration, counted vmcnt.
#define BM1 256
#define BN1 128
#define A1SZ (BM1*BK)    // 8192 ushorts = 16KB
#define W1SZ (BN1*BK)    // 4096 ushorts = 8KB

__global__ __launch_bounds__(512, 2) void k_gemm1(
    const unsigned short* __restrict__ xbf,
    const unsigned short* __restrict__ w1t, const unsigned short* __restrict__ w2t,
    const float* __restrict__ b1, const float* __restrict__ b2,
    const int* __restrict__ counts, const int* __restrict__ offsets,
    const int* __restrict__ slot_token,
    unsigned short* __restrict__ hh) {
    int e = blockIdx.z;
    int n_e = counts[e];
    int m0 = blockIdx.y * BM1;
    if (m0 >= n_e) return;
    int base = offsets[e];
    int n0 = blockIdx.x * BN1;

    __shared__ __align__(16) unsigned short sA[3*A1SZ];    // 48KB
    __shared__ __align__(16) unsigned short sW1[3*W1SZ];   // 24KB
    __shared__ __align__(16) unsigned short sW2[3*W1SZ];   // 24KB
    __shared__ int tlist[BM1];

    int tid = threadIdx.x;
    if (tid < BM1) {
        int r = m0 + tid; if (r > n_e - 1) r = n_e - 1;    // pad tiles with a valid row
        tlist[tid] = slot_token[base + r];
    }
    __syncthreads();

    int wid = tid >> 6, lane = tid & 63;
    int wr = wid >> 1, wc = wid & 1;

    // staging: wave w -> A rows [w*32,w*32+32), W rows [w*16,w*16+16)
    int rl = lane >> 2, sc_ = lane & 3;
    int rA0 = wid*32 + rl, rA1 = rA0 + 16;
    int rB  = wid*16 + rl;
    int cA0 = sc_ ^ ((rA0 >> 1) & 3);
    int cA1 = sc_ ^ ((rA1 >> 1) & 3);
    int cB  = sc_ ^ ((rB  >> 1) & 3);
    int tA0 = tlist[rA0], tA1 = tlist[rA1];
    const unsigned short* pa0 = xbf + (size_t)tA0*Dc + cA0*8;
    const unsigned short* pa1 = xbf + (size_t)tA1*Dc + cA1*8;
    const size_t wb = ((size_t)e * Hc + n0) * Dc;
    const unsigned short* pw1 = w1t + wb + (size_t)rB*Dc + cB*8;
    const unsigned short* pw2 = w2t + wb + (size_t)rB*Dc + cB*8;
    int aofs = wid*1024, bofs = wid*512;

    f32x4 acc1[4][4], acc2[4][4];
    #pragma unroll
    for (int m = 0; m < 4; m++)
        #pragma unroll
        for (int n = 0; n < 4; n++)
            #pragma unroll
            for (int j = 0; j < 4; j++) { acc1[m][n][j] = 0.0f; acc2[m][n][j] = 0.0f; }

    // fragment LDS offsets (XOR chunk swizzle; (rr>>1)&3 reduces to (arow>>1)&3)
    int arow = lane & 15, cr = lane >> 4;
    int ccf = cr ^ ((arow >> 1) & 3);
    int offA[4], offW[4];
    #pragma unroll
    for (int m = 0; m < 4; m++) offA[m] = (wr*64 + m*16 + arow)*BK + ccf*8;
    #pragma unroll
    for (int n = 0; n < 4; n++) offW[n] = (wc*64 + n*16 + arow)*BK + ccf*8;

    auto STAGE = [&](int buf, int kk) {    // 4 loads per tile
        unsigned short* dA = sA + buf*A1SZ + aofs;
        gload16(pa0 + kk, dA);
        gload16(pa1 + kk, dA + 512);
        gload16(pw1 + kk, sW1 + buf*W1SZ + bofs);
        gload16(pw2 + kk, sW2 + buf*W1SZ + bofs);
    };

#define LDF1(buf, a, w1f, w2f) { \
    const unsigned short* lA_ = sA  + (buf)*A1SZ; \
    const unsigned short* l1_ = sW1 + (buf)*W1SZ; \
    const unsigned short* l2_ = sW2 + (buf)*W1SZ; \
    _Pragma("unroll") for (int m_ = 0; m_ < 4; m_++) a[m_] = *(const bf16x8*)&lA_[offA[m_]]; \
    _Pragma("unroll") for (int n_ = 0; n_ < 4; n_++) { \
        w1f[n_] = *(const bf16x8*)&l1_[offW[n_]]; \
        w2f[n_] = *(const bf16x8*)&l2_[offW[n_]]; } }

#define MM1(a, w1f, w2f) { \
    _Pragma("unroll") for (int m_ = 0; m_ < 4; m_++) \
        _Pragma("unroll") for (int n_ = 0; n_ < 4; n_++) { \
            acc1[m_][n_] = __builtin_amdgcn_mfma_f32_16x16x32_bf16(a[m_], w1f[n_], acc1[m_][n_], 0, 0, 0); \
            acc2[m_][n_] = __builtin_amdgcn_mfma_f32_16x16x32_bf16(a[m_], w2f[n_], acc2[m_][n_], 0, 0, 0); } }

    bf16x8 a0[4], x10[4], x20[4], a1[4], x11[4], x21[4];

    // prologue: tiles 0,1 in flight; drain tile0; read frags[0]
    STAGE(0, 0); STAGE(1, BK);
    asm volatile("s_waitcnt vmcnt(4)" ::: "memory");
    fence_bar();
    LDF1(0, a0, x10, x20);
    asm volatile("s_waitcnt lgkmcnt(0)" ::: "memory");
    __builtin_amdgcn_sched_barrier(0);

    const int NT = Dc / BK;   // 32 (even)
    int ib = 0;               // slot of tile t

#define G1ITER(T, CA, CW1, CW2, NA, NW1, NW2) { \
    int i1_ = ib + 1; if (i1_ == 3) i1_ = 0; \
    int i2_ = i1_ + 1; if (i2_ == 3) i2_ = 0; \
    if ((T) + 2 < NT) { \
        STAGE(i2_, ((T)+2)*BK); \
        asm volatile("s_waitcnt vmcnt(4)" ::: "memory");   /* tile T+1 landed */ \
    } else if ((T) + 1 < NT) { \
        asm volatile("s_waitcnt vmcnt(0)" ::: "memory"); \
    } \
    fence_bar();                                /* publish slot i1_; license WAR on i2_ */ \
    __builtin_amdgcn_s_setprio(1); \
    if ((T) + 1 < NT) LDF1(i1_, NA, NW1, NW2);  /* ds_read ∥ MFMA: no wait between */ \
    MM1(CA, CW1, CW2); \
    __builtin_amdgcn_s_setprio(0); \
    asm volatile("s_waitcnt lgkmcnt(0)" ::: "memory"); \
    __builtin_amdgcn_sched_barrier(0); \
    ib = i1_; }

    for (int t = 0; t < NT; t += 2) {
        G1ITER(t,   a0, x10, x20, a1, x11, x21);
        G1ITER(t+1, a1, x11, x21, a0, x10, x20);
    }

    // epilogue: C/D layout col=lane&15, row=(lane>>4)*4+j
    int lrow = (lane >> 4) * 4, lcol = lane & 15;
    #pragma unroll
    for (int n = 0; n < 4; n++) {
        int hcol = n0 + wc*64 + n*16 + lcol;
        float bias1 = b1[e*Hc + hcol], bias2 = b2[e*Hc + hcol];
        #pragma unroll
        for (int m = 0; m < 4; m++) {
            int rb2 = m0 + wr*64 + m*16 + lrow;
            #pragma unroll
            for (int j = 0; j < 4; j++) {
                int r = rb2 + j;
                if (r < n_e) {
                    float h1v = acc1[m][n][j] + bias1;
                    float h2v = acc2[m][n][j] + bias2;
                    float hhv = h1v * (h2v / (1.0f + expf(-h2v)));   // h1 * silu(h2)
                    hh[(size_t)(base + r)*Hc + hcol] = f2bf(hhv);
                }
            }
        }
    }
#undef G1ITER
#undef MM1
#undef LDF1
}

// ---------------- GEMM2: OUT = HH @ Wp^T + bp, per expert ----------------
// Same pipeline: 256x128 tile, BK=32, 3-slot ring, reg-prefetch ∥ MFMA, 1 bar/iter.
#define BM2 256
#define BN2 128
#define A2SZ (BM2*BK)    // 8192 ushorts = 16KB
#define B2SZ (BN2*BK)    // 4096 ushorts = 8KB

__global__ __launch_bounds__(512, 2) void k_gemm2(
    const unsigned short* __restrict__ hh,
    const unsigned short* __restrict__ wpt,
    const float* __restrict__ bp,
    const int* __restrict__ counts, const int* __restrict__ offsets,
    float* __restrict__ outb) {
    int e = blockIdx.z;
    int n_e = counts[e];
    int m0 = blockIdx.y * BM2;
    if (m0 >= n_e) return;
    int base = offsets[e];
    int n0 = blockIdx.x * BN2;

    __shared__ __align__(16) unsigned short sA[3*A2SZ];   // 48KB
    __shared__ __align__(16) unsigned short sB[3*B2SZ];   // 24KB

    int tid = threadIdx.x;
    int wid = tid >> 6, lane = tid & 63;
    int wr = wid >> 1, wc = wid & 1;

    int rl = lane >> 2, sc_ = lane & 3;
    int rA0 = wid*32 + rl, rA1 = rA0 + 16;
    int rB  = wid*16 + rl;
    int cA0 = sc_ ^ ((rA0 >> 1) & 3);
    int cA1 = sc_ ^ ((rA1 >> 1) & 3);
    int cB  = sc_ ^ ((rB  >> 1) & 3);
    int gr0 = m0 + rA0; if (gr0 > n_e - 1) gr0 = n_e - 1;
    int gr1 = m0 + rA1; if (gr1 > n_e - 1) gr1 = n_e - 1;
    const unsigned short* pa0 = hh + (size_t)(base + gr0)*Hc + cA0*8;
    const unsigned short* pa1 = hh + (size_t)(base + gr1)*Hc + cA1*8;
    const unsigned short* pb  = wpt + ((size_t)e*Dc + n0 + rB)*Hc + cB*8;
    int aofs = wid*1024, bofs = wid*512;

    f32x4 acc[4][4];
    #pragma unroll
    for (int m = 0; m < 4; m++)
        #pragma unroll
        for (int n = 0; n < 4; n++)
            #pragma unroll
            for (int j = 0; j < 4; j++) acc[m][n][j] = 0.0f;

    int arow = lane & 15, cr = lane >> 4;
    int ccf = cr ^ ((arow >> 1) & 3);
    int offA[4], offW[4];
    #pragma unroll
    for (int m = 0; m < 4; m++) offA[m] = (wr*64 + m*16 + arow)*BK + ccf*8;
    #pragma unroll
    for (int n = 0; n < 4; n++) offW[n] = (wc*64 + n*16 + arow)*BK + ccf*8;

    auto STAGE = [&](int buf, int kk) {    // 3 loads per tile
        unsigned short* dA = sA + buf*A2SZ + aofs;
        gload16(pa0 + kk, dA);
        gload16(pa1 + kk, dA + 512);
        gload16(pb  + kk, sB + buf*B2SZ + bofs);
    };

#define LDF2(buf, a, b) { \
    const unsigned short* lA_ = sA + (buf)*A2SZ; \
    const unsigned short* lB_ = sB + (buf)*B2SZ; \
    _Pragma("unroll") for (int m_ = 0; m_ < 4; m_++) a[m_] = *(const bf16x8*)&lA_[offA[m_]]; \
    _Pragma("unroll") for (int n_ = 0; n_ < 4; n_++) b[n_] = *(const bf16x8*)&lB_[offW[n_]]; }

#define MM2(a, b) { \
    _Pragma("unroll") for (int m_ = 0; m_ < 4; m_++) \
        _Pragma("unroll") for (int n_ = 0; n_ < 4; n_++) \
            acc[m_][n_] = __builtin_amdgcn_mfma_f32_16x16x32_bf16(a[m_], b[n_], acc[m_][n_], 0, 0, 0); }

    bf16x8 a0[4], b0[4], a1[4], b1f[4];

    STAGE(0, 0); STAGE(1, BK);
    asm volatile("s_waitcnt vmcnt(3)" ::: "memory");   // tile0 (3 loads) drained
    fence_bar();
    LDF2(0, a0, b0);
    asm volatile("s_waitcnt lgkmcnt(0)" ::: "memory");
    __builtin_amdgcn_sched_barrier(0);

    const int NT = Hc / BK;   // 128 (even)
    int ib = 0;

#define G2ITER(T, CA, CB, NA, NB) { \
    int i1_ = ib + 1; if (i1_ == 3) i1_ = 0; \
    int i2_ = i1_ + 1; if (i2_ == 3) i2_ = 0; \
    if ((T) + 2 < NT) { \
        STAGE(i2_, ((T)+2)*BK); \
        asm volatile("s_waitcnt vmcnt(3)" ::: "memory"); \
    } else if ((T) + 1 < NT) { \
        asm volatile("s_waitcnt vmcnt(0)" ::: "memory"); \
    } \
    fence_bar(); \
    __builtin_amdgcn_s_setprio(1); \
    if ((T) + 1 < NT) LDF2(i1_, NA, NB); \
    MM2(CA, CB); \
    __builtin_amdgcn_s_setprio(0); \
    asm volatile("s_waitcnt lgkmcnt(0)" ::: "memory"); \
    __builtin_amdgcn_sched_barrier(0); \
    ib = i1_; }

    for (int t = 0; t < NT; t += 2) {
        G2ITER(t,   a0, b0, a1, b1f);
        G2ITER(t+1, a1, b1f, a0, b0);
    }

    int lrow = (lane >> 4) * 4, lcol = lane & 15;
    #pragma unroll
    for (int n = 0; n < 4; n++) {
        int dcol = n0 + wc*64 + n*16 + lcol;
        float bias = bp[e*Dc + dcol];
        #pragma unroll
        for (int m = 0; m < 4; m++) {
            int rb2 = m0 + wr*64 + m*16 + lrow;
            #pragma unroll
            for (int j = 0; j < 4; j++) {
                int r = rb2 + j;
                if (r < n_e)
                    outb[(size_t)(base + r)*Dc + dcol] = acc[m][n][j] + bias;
            }
        }
    }
#undef G2ITER
#undef MM2
#undef LDF2
}

// ---------------- combine: final[t] = w0*OUT[s0] + w1*OUT[s1] ----------------
__global__ void k_combine(const float* __restrict__ outb, const int* __restrict__ slot_of,
                          const float* __restrict__ tok_w, float* __restrict__ final_out) {
    int gid = blockIdx.x * 256 + threadIdx.x;   // Tc*Dc/4 threads
    int t = gid >> 8;
    int c = (gid & 255) * 4;
    int s0 = slot_of[t*2], s1 = slot_of[t*2 + 1];
    float w0 = tok_w[t*2], w1 = tok_w[t*2 + 1];
    float4 o0 = *(const float4*)&outb[(size_t)s0*Dc + c];
    float4 o1 = *(const float4*)&outb[(size_t)s1*Dc + c];
    float4 r;
    r.x = w0*o0.x + w1*o1.x;
    r.y = w0*o0.y + w1*o1.y;
    r.z = w0*o0.z + w1*o1.z;
    r.w = w0*o0.w + w1*o1.w;
    *(float4*)&final_out[(size_t)t*Dc + c] = r;
}

extern "C" void kernel_launch(void* const* d_in, const int* in_sizes, int n_in,
                              void* d_out, int out_size, void* d_ws, size_t ws_size,
                              hipStream_t stream) {
    (void)in_sizes; (void)n_in; (void)out_size; (void)ws_size;
    const float* x     = (const float*)d_in[0];
    const float* noise = (const float*)d_in[1];
    const float* Wg    = (const float*)d_in[2];
    const float* nw    = (const float*)d_in[3];
    const float* W1    = (const float*)d_in[4];
    const float* b1    = (const float*)d_in[5];
    const float* W2    = (const float*)d_in[6];
    const float* b2    = (const float*)d_in[7];
    const float* Wp    = (const float*)d_in[8];
    const float* bp    = (const float*)d_in[9];

    char* ws = (char*)d_ws;
    size_t off = 0;
    unsigned short* XBF = (unsigned short*)(ws + off); off += (size_t)Tc*Dc*2;       // 8 MB
    unsigned short* W1T = (unsigned short*)(ws + off); off += (size_t)Ec*Dc*Hc*2;    // 64 MB
    unsigned short* W2T = (unsigned short*)(ws + off); off += (size_t)Ec*Dc*Hc*2;    // 64 MB
    unsigned short* WPT = (unsigned short*)(ws + off); off += (size_t)Ec*Hc*Dc*2;    // 64 MB
    unsigned short* HH  = (unsigned short*)(ws + off); off += (size_t)NSLOT*Hc*2;    // 64 MB
    float*          OUTB= (float*)(ws + off);          off += (size_t)NSLOT*Dc*4;    // 32 MB
    int*   counts    = (int*)(ws + off);
    int*   fill      = (int*)(ws + off + 32);
    int*   offsets   = (int*)(ws + off + 64);
    int*   tok_top   = (int*)(ws + off + 128);
    float* tok_w     = (float*)(ws + off + 128 + (size_t)Tc*2*4);
    int*   slot_token= (int*)(ws + off + 128 + (size_t)Tc*2*8);
    int*   slot_of   = (int*)(ws + off + 128 + (size_t)Tc*2*8 + (size_t)NSLOT*4);

    float* final_out = (float*)d_out;
    float* idx_out   = (float*)d_out + FINAL_N;

    hipMemsetAsync(counts, 0, 64, stream);   // counts + fill

    k_cvt_x<<<(Tc*Dc/8)/256, 256, 0, stream>>>(x, XBF);
    // W1 + W2 transposes in one launch (z = 16: [0,8) -> W1, [8,16) -> W2)
    k_transpose_cvt2<<<dim3(Hc/64, Dc/64, 2*Ec), 256, 0, stream>>>(W1, W2, W1T, W2T, Dc, Hc, Ec);
    k_transpose_cvt2<<<dim3(Dc/64, Hc/64, Ec), 256, 0, stream>>>(Wp, Wp, WPT, WPT, Hc, Dc, Ec);

    k_gate<<<Tc, 64, 0, stream>>>(x, noise, Wg, nw, idx_out, counts, tok_top, tok_w);
    k_scan<<<1, 64, 0, stream>>>(counts, offsets);
    k_fill<<<Tc/256, 256, 0, stream>>>(tok_top, offsets, fill, slot_token, slot_of);

    k_gemm1<<<dim3(Hc/BN1, Tc/BM1, Ec), 512, 0, stream>>>(XBF, W1T, W2T, b1, b2,
                                                          counts, offsets, slot_token, HH);
    k_gemm2<<<dim3(Dc/BN2, Tc/BM2, Ec), 512, 0, stream>>>(HH, WPT, bp, counts, offsets, OUTB);
    k_combine<<<(Tc*Dc/4)/256, 256, 0, stream>>>(OUTB, slot_of, tok_w, final_out);
}

// Round 3
// 696.903 us; speedup vs baseline: 1.0089x; 1.0089x over previous
//
#include <hip/hip_runtime.h>
#include <math.h>

// MoE: B=2 S=2048 D=1024 E=8 H=4096 K=2
#define Bc 2
#define Sc 2048
#define Dc 1024
#define Ec 8
#define Hc 4096
#define Tc (Bc*Sc)          // 4096 tokens
#define NSLOT (Tc*2)        // 8192 token-expert slots (top-2 always)
#define SLOTPAD 8448        // NSLOT + 256 slack rows (padded tile over-read)
#define FINAL_N ((size_t)Tc*Dc)
#define BK 32               // K-panel (bf16 elems) = 64B per row = 4x 16B chunks
#define PROWS ((size_t)SLOTPAD*32)   // ushorts per K-panel of A/HH

typedef float f32x4 __attribute__((ext_vector_type(4)));
typedef __bf16 bf16x8 __attribute__((ext_vector_type(8)));

__device__ __forceinline__ unsigned short f2bf(float f) {
    union { float f; unsigned int u; } v; v.f = f;
    return (unsigned short)((v.u + 0x7fffu + ((v.u >> 16) & 1u)) >> 16);
}
__device__ __forceinline__ unsigned int pack2bf(float a, float b) {
    return (unsigned int)f2bf(a) | ((unsigned int)f2bf(b) << 16);
}

// async global->LDS, 16B per lane. LDS dest = uniform base + lane*16 (linear).
// Global source is CONTIGUOUS 1KB per instruction (panel-major packed operands).
__device__ __forceinline__ void gload16(const unsigned short* g, unsigned short* l) {
    __builtin_amdgcn_global_load_lds(
        (const __attribute__((address_space(1))) unsigned int*)g,
        (__attribute__((address_space(3))) unsigned int*)l,
        16, 0, 0);
}

// raw barrier with compiler fences (NO vmcnt(0) drain, unlike __syncthreads)
__device__ __forceinline__ void fence_bar() {
    __builtin_amdgcn_sched_barrier(0);
    asm volatile("s_barrier" ::: "memory");
    __builtin_amdgcn_sched_barrier(0);
}

// ------- [R][C] fp32 -> panel-major bf16 [C/128][R/32][128][32], chunk-XOR pre-swizzled -------
// value (r,c) -> out[((c>>7)*R32 + (r>>5))*4096 + (c&127)*32 + ((((r>>3)&3) ^ (((c&127)>>1)&3))*8) + (r&7)]
__global__ void k_transpose_panel(const float* __restrict__ inA, const float* __restrict__ inB,
                                  unsigned short* __restrict__ outA, unsigned short* __restrict__ outB,
                                  int R, int C, int nz_per_mat) {
    __shared__ float tile[64][65];
    int z = blockIdx.z;
    const float* in; unsigned short* out;
    if (z < nz_per_mat) { in = inA; out = outA; }
    else { in = inB; out = outB; z -= nz_per_mat; }
    size_t zbase = (size_t)z * (size_t)R * C;
    int R32 = R >> 5;
    int cb = blockIdx.x * 64, rb = blockIdx.y * 64;
    int t = threadIdx.x;             // 256
    int q = t & 15, g = t >> 4;
    #pragma unroll
    for (int j = 0; j < 4; j++) {
        int row = g + 16*j;
        float4 v = *(const float4*)&in[zbase + (size_t)(rb+row)*C + cb + q*4];
        tile[row][q*4+0] = v.x; tile[row][q*4+1] = v.y;
        tile[row][q*4+2] = v.z; tile[row][q*4+3] = v.w;
    }
    __syncthreads();
    #pragma unroll
    for (int j = 0; j < 4; j++) {
        int co = g + 16*j;
        int c = cb + co;
        int r0 = rb + q*4;                     // 4 consecutive r within one 8-chunk half
        ushort4 o;
        o.x = f2bf(tile[q*4+0][co]); o.y = f2bf(tile[q*4+1][co]);
        o.z = f2bf(tile[q*4+2][co]); o.w = f2bf(tile[q*4+3][co]);
        int cr = c & 127;
        int ch = ((r0 >> 3) & 3) ^ ((cr >> 1) & 3);
        size_t off = zbase + (((size_t)(c >> 7) * R32 + (r0 >> 5)) * 4096)
                   + (size_t)cr * 32 + ch * 8 + (r0 & 7);
        *(ushort4*)&out[off] = o;
    }
}

// ---------------- gating: one wave per token ----------------
__global__ void k_gate(const float* __restrict__ x, const float* __restrict__ noise,
                       const float* __restrict__ Wg, const float* __restrict__ nw,
                       float* __restrict__ out_idx, int* __restrict__ counts,
                       int* __restrict__ tok_top, float* __restrict__ tok_w) {
    int t = blockIdx.x;
    int lane = threadIdx.x;                     // 64
    const float* xr = x + (size_t)t * Dc;
    double acc[Ec];
    #pragma unroll
    for (int e = 0; e < Ec; e++) acc[e] = 0.0;
    for (int i = 0; i < Dc/64; i++) {
        int d = lane + i*64;
        double xv = (double)xr[d];
        #pragma unroll
        for (int e = 0; e < Ec; e++) acc[e] += xv * (double)Wg[e*Dc + d];
    }
    #pragma unroll
    for (int e = 0; e < Ec; e++)
        for (int off = 32; off > 0; off >>= 1)
            acc[e] += __shfl_down(acc[e], off);
    if (lane == 0) {
        double noisy[Ec];
        #pragma unroll
        for (int e = 0; e < Ec; e++)
            noisy[e] = acc[e] + (double)noise[t*Ec + e] * (double)nw[e];
        int i0 = 0;
        for (int e = 1; e < Ec; e++) if (noisy[e] > noisy[i0]) i0 = e;   // ties -> lowest idx
        int i1 = -1;
        for (int e = 0; e < Ec; e++) {
            if (e == i0) continue;
            if (i1 < 0 || noisy[e] > noisy[i1]) i1 = e;
        }
        double ee = exp(noisy[i1] - noisy[i0]);   // v1 <= v0, stable
        float w0 = (float)(1.0 / (1.0 + ee));
        float w1 = (float)(ee / (1.0 + ee));
        out_idx[t*2 + 0] = (float)i0;
        out_idx[t*2 + 1] = (float)i1;
        tok_top[t*2] = i0; tok_top[t*2+1] = i1;
        tok_w[t*2] = w0;   tok_w[t*2+1] = w1;
        atomicAdd(&counts[i0], 1);
        atomicAdd(&counts[i1], 1);
    }
}

__global__ void k_scan(const int* __restrict__ counts, int* __restrict__ offsets) {
    if (threadIdx.x == 0) {
        int s = 0;
        for (int e = 0; e < Ec; e++) { offsets[e] = s; s += counts[e]; }
        offsets[Ec] = s;
    }
}

__global__ void k_fill(const int* __restrict__ tok_top, const int* __restrict__ offsets,
                       int* __restrict__ fill, int* __restrict__ slot_token,
                       int* __restrict__ slot_of, int* __restrict__ slot_pos) {
    int t = blockIdx.x * 256 + threadIdx.x;
    if (t >= Tc) return;
    #pragma unroll
    for (int j = 0; j < 2; j++) {
        int e = tok_top[t*2 + j];
        int pos = atomicAdd(&fill[e], 1);
        int slot = offsets[e] + pos;
        slot_token[slot] = t;
        slot_of[t*2 + j] = slot;
        slot_pos[slot] = pos;                 // expert-local row (swizzle key source)
    }
}

// ---- pack A: gather + cvt into K-panel-major APK[kp=32][SLOTPAD][32], pre-swizzled ----
// one wave per slot; lane covers k in [lane*16, lane*16+16)
__global__ void k_packA(const float* __restrict__ x, const int* __restrict__ slot_token,
                        const int* __restrict__ slot_pos, unsigned short* __restrict__ apk) {
    int s = blockIdx.x * 4 + (threadIdx.x >> 6);
    int lane = threadIdx.x & 63;
    int token = slot_token[s];
    int pos = slot_pos[s];
    const float4* px = (const float4*)(x + (size_t)token * Dc) + lane*4;
    float4 v0 = px[0], v1 = px[1], v2 = px[2], v3 = px[3];
    uint4 lo, hi;
    lo.x = pack2bf(v0.x, v0.y); lo.y = pack2bf(v0.z, v0.w);
    lo.z = pack2bf(v1.x, v1.y); lo.w = pack2bf(v1.z, v1.w);
    hi.x = pack2bf(v2.x, v2.y); hi.y = pack2bf(v2.z, v2.w);
    hi.z = pack2bf(v3.x, v3.y); hi.w = pack2bf(v3.z, v3.w);
    int kp = lane >> 1;
    int key = (pos >> 1) & 3;
    int c0 = (lane & 1) * 2;
    size_t base = (size_t)kp * PROWS + (size_t)s * 32;
    *(uint4*)&apk[base + ((c0 ^ key) * 8)]       = lo;
    *(uint4*)&apk[base + (((c0+1) ^ key) * 8)]   = hi;
}

// ---------------- GEMM1: HH = (X@W1+b1) * silu(X@W2+b2), per expert ----------------
// 256x128 tile, BK=32, 8 waves (4Mx2N), 64x64/wave/matrix.
// Panel-major operands -> fully contiguous 1KB DMA per gload16 (no LDS-write scatter).
// 3-slot LDS ring, reg-prefetch of next-iter frags inside MFMA region, 1 barrier/iter.
#define BM1 256
#define BN1 128
#define A1SZ (BM1*BK)    // 8192 ushorts = 16KB
#define W1SZ (BN1*BK)    // 4096 ushorts = 8KB

__global__ __launch_bounds__(512, 2) void k_gemm1(
    const unsigned short* __restrict__ apk,
    const unsigned short* __restrict__ w1p, const unsigned short* __restrict__ w2p,
    const float* __restrict__ b1, const float* __restrict__ b2,
    const int* __restrict__ counts, const int* __restrict__ offsets,
    unsigned short* __restrict__ hh2) {
    int e = blockIdx.z;
    int n_e = counts[e];
    int m0 = blockIdx.y * BM1;
    if (m0 >= n_e) return;
    int base = offsets[e];
    int hp = blockIdx.x;                 // BN1=128 -> h-panel index
    int n0 = hp * BN1;

    __shared__ __align__(16) unsigned short sA[3*A1SZ];    // 48KB
    __shared__ __align__(16) unsigned short sW1[3*W1SZ];   // 24KB
    __shared__ __align__(16) unsigned short sW2[3*W1SZ];   // 24KB

    int tid = threadIdx.x;
    int wid = tid >> 6, lane = tid & 63;
    int wr = wid >> 1, wc = wid & 1;

    // contiguous staging sources (per K-step: A += kp*PROWS, W += kp*4096)
    const unsigned short* pa  = apk + (size_t)(base + m0 + wid*32) * 32 + lane*8;
    const unsigned short* pw1 = w1p + ((size_t)(e*32 + hp) * 32) * 4096 + wid*512 + lane*8;
    const unsigned short* pw2 = w2p + ((size_t)(e*32 + hp) * 32) * 4096 + wid*512 + lane*8;

    f32x4 acc1[4][4], acc2[4][4];
    #pragma unroll
    for (int m = 0; m < 4; m++)
        #pragma unroll
        for (int n = 0; n < 4; n++)
            #pragma unroll
            for (int j = 0; j < 4; j++) { acc1[m][n][j] = 0.0f; acc2[m][n][j] = 0.0f; }

    // fragment LDS offsets (pre-swizzled layout: chunk = cr ^ ((row>>1)&3))
    int arow = lane & 15, cr = lane >> 4;
    int ccf = cr ^ ((arow >> 1) & 3);
    int offA[4], offW[4];
    #pragma unroll
    for (int m = 0; m < 4; m++) offA[m] = (wr*64 + m*16 + arow)*BK + ccf*8;
    #pragma unroll
    for (int n = 0; n < 4; n++) offW[n] = (wc*64 + n*16 + arow)*BK + ccf*8;

    auto STAGE = [&](int buf, int kp) {    // 4 loads per wave, all contiguous 1KB
        unsigned short* dA = sA + buf*A1SZ + wid*1024;
        const unsigned short* a = pa + (size_t)kp * PROWS;
        gload16(a,       dA);
        gload16(a + 512, dA + 512);
        gload16(pw1 + kp*4096, sW1 + buf*W1SZ + wid*512);
        gload16(pw2 + kp*4096, sW2 + buf*W1SZ + wid*512);
    };

#define LDF1(buf, a, w1f, w2f) { \
    const unsigned short* lA_ = sA  + (buf)*A1SZ; \
    const unsigned short* l1_ = sW1 + (buf)*W1SZ; \
    const unsigned short* l2_ = sW2 + (buf)*W1SZ; \
    _Pragma("unroll") for (int m_ = 0; m_ < 4; m_++) a[m_] = *(const bf16x8*)&lA_[offA[m_]]; \
    _Pragma("unroll") for (int n_ = 0; n_ < 4; n_++) { \
        w1f[n_] = *(const bf16x8*)&l1_[offW[n_]]; \
        w2f[n_] = *(const bf16x8*)&l2_[offW[n_]]; } }

#define MM1(a, w1f, w2f) { \
    _Pragma("unroll") for (int m_ = 0; m_ < 4; m_++) \
        _Pragma("unroll") for (int n_ = 0; n_ < 4; n_++) { \
            acc1[m_][n_] = __builtin_amdgcn_mfma_f32_16x16x32_bf16(a[m_], w1f[n_], acc1[m_][n_], 0, 0, 0); \
            acc2[m_][n_] = __builtin_amdgcn_mfma_f32_16x16x32_bf16(a[m_], w2f[n_], acc2[m_][n_], 0, 0, 0); } }

    bf16x8 a0[4], x10[4], x20[4], a1[4], x11[4], x21[4];

    STAGE(0, 0); STAGE(1, 1);
    asm volatile("s_waitcnt vmcnt(4)" ::: "memory");
    fence_bar();
    LDF1(0, a0, x10, x20);
    asm volatile("s_waitcnt lgkmcnt(0)" ::: "memory");
    __builtin_amdgcn_sched_barrier(0);

    const int NT = Dc / BK;   // 32 (even)
    int ib = 0;               // slot of tile t

#define G1ITER(T, CA, CW1, CW2, NA, NW1, NW2) { \
    int i1_ = ib + 1; if (i1_ == 3) i1_ = 0; \
    int i2_ = i1_ + 1; if (i2_ == 3) i2_ = 0; \
    if ((T) + 2 < NT) { \
        STAGE(i2_, (T)+2); \
        asm volatile("s_waitcnt vmcnt(4)" ::: "memory");   /* tile T+1 landed */ \
    } else if ((T) + 1 < NT) { \
        asm volatile("s_waitcnt vmcnt(0)" ::: "memory"); \
    } \
    fence_bar();                                /* publish slot i1_; license WAR on i2_ */ \
    __builtin_amdgcn_s_setprio(1); \
    if ((T) + 1 < NT) LDF1(i1_, NA, NW1, NW2);  /* ds_read ∥ MFMA: no wait between */ \
    MM1(CA, CW1, CW2); \
    __builtin_amdgcn_s_setprio(0); \
    asm volatile("s_waitcnt lgkmcnt(0)" ::: "memory"); \
    __builtin_amdgcn_sched_barrier(0); \
    ib = i1_; }

    for (int t = 0; t < NT; t += 2) {
        G1ITER(t,   a0, x10, x20, a1, x11, x21);
        G1ITER(t+1, a1, x11, x21, a0, x10, x20);
    }

    // epilogue -> HH2 panel-major [hp2=128][SLOTPAD][32], chunk-XOR key = expert-local row
    int lrow = (lane >> 4) * 4, lcol = lane & 15;
    #pragma unroll
    for (int n = 0; n < 4; n++) {
        int hcol = n0 + wc*64 + n*16 + lcol;
        float bias1 = b1[e*Hc + hcol], bias2 = b2[e*Hc + hcol];
        int hp2 = hcol >> 5;
        int ch  = (hcol >> 3) & 3;
        int ho  = hcol & 7;
        #pragma unroll
        for (int m = 0; m < 4; m++) {
            int rb2 = m0 + wr*64 + m*16 + lrow;
            #pragma unroll
            for (int j = 0; j < 4; j++) {
                int r = rb2 + j;
                if (r < n_e) {
                    float h1v = acc1[m][n][j] + bias1;
                    float h2v = acc2[m][n][j] + bias2;
                    float hhv = h1v * (h2v / (1.0f + expf(-h2v)));   // h1 * silu(h2)
                    int key = (r >> 1) & 3;
                    hh2[(size_t)hp2 * PROWS + (size_t)(base + r)*32 + ((ch ^ key)*8) + ho] = f2bf(hhv);
                }
            }
        }
    }
#undef G1ITER
#undef MM1
#undef LDF1
}

// ---------------- GEMM2: OUT = HH @ Wp^T + bp, per expert ----------------
// Same pipeline; A = HH2 panel-major, B = WPP panel-major; contiguous DMA.
#define BM2 256
#define BN2 128
#define A2SZ (BM2*BK)    // 8192 ushorts = 16KB
#define B2SZ (BN2*BK)    // 4096 ushorts = 8KB

__global__ __launch_bounds__(512, 2) void k_gemm2(
    const unsigned short* __restrict__ hh2,
    const unsigned short* __restrict__ wpp,
    const float* __restrict__ bp,
    const int* __restrict__ counts, const int* __restrict__ offsets,
    float* __restrict__ outb) {
    int e = blockIdx.z;
    int n_e = counts[e];
    int m0 = blockIdx.y * BM2;
    if (m0 >= n_e) return;
    int base = offsets[e];
    int dp = blockIdx.x;
    int n0 = dp * BN2;

    __shared__ __align__(16) unsigned short sA[3*A2SZ];   // 48KB
    __shared__ __align__(16) unsigned short sB[3*B2SZ];   // 24KB

    int tid = threadIdx.x;
    int wid = tid >> 6, lane = tid & 63;
    int wr = wid >> 1, wc = wid & 1;

    const unsigned short* pa = hh2 + (size_t)(base + m0 + wid*32) * 32 + lane*8;
    const unsigned short* pb = wpp + ((size_t)(e*8 + dp) * 128) * 4096 + wid*512 + lane*8;

    f32x4 acc[4][4];
    #pragma unroll
    for (int m = 0; m < 4; m++)
        #pragma unroll
        for (int n = 0; n < 4; n++)
            #pragma unroll
            for (int j = 0; j < 4; j++) acc[m][n][j] = 0.0f;

    int arow = lane & 15, cr = lane >> 4;
    int ccf = cr ^ ((arow >> 1) & 3);
    int offA[4], offW[4];
    #pragma unroll
    for (int m = 0; m < 4; m++) offA[m] = (wr*64 + m*16 + arow)*BK + ccf*8;
    #pragma unroll
    for (int n = 0; n < 4; n++) offW[n] = (wc*64 + n*16 + arow)*BK + ccf*8;

    auto STAGE = [&](int buf, int kp) {    // 3 loads per wave, contiguous
        unsigned short* dA = sA + buf*A2SZ + wid*1024;
        const unsigned short* a = pa + (size_t)kp * PROWS;
        gload16(a,       dA);
        gload16(a + 512, dA + 512);
        gload16(pb + kp*4096, sB + buf*B2SZ + wid*512);
    };

#define LDF2(buf, a, b) { \
    const unsigned short* lA_ = sA + (buf)*A2SZ; \
    const unsigned short* lB_ = sB + (buf)*B2SZ; \
    _Pragma("unroll") for (int m_ = 0; m_ < 4; m_++) a[m_] = *(const bf16x8*)&lA_[offA[m_]]; \
    _Pragma("unroll") for (int n_ = 0; n_ < 4; n_++) b[n_] = *(const bf16x8*)&lB_[offW[n_]]; }

#define MM2(a, b) { \
    _Pragma("unroll") for (int m_ = 0; m_ < 4; m_++) \
        _Pragma("unroll") for (int n_ = 0; n_ < 4; n_++) \
            acc[m_][n_] = __builtin_amdgcn_mfma_f32_16x16x32_bf16(a[m_], b[n_], acc[m_][n_], 0, 0, 0); }

    bf16x8 a0[4], b0[4], a1[4], b1f[4];

    STAGE(0, 0); STAGE(1, 1);
    asm volatile("s_waitcnt vmcnt(3)" ::: "memory");   // tile0 (3 loads) drained
    fence_bar();
    LDF2(0, a0, b0);
    asm volatile("s_waitcnt lgkmcnt(0)" ::: "memory");
    __builtin_amdgcn_sched_barrier(0);

    const int NT = Hc / BK;   // 128 (even)
    int ib = 0;

#define G2ITER(T, CA, CB, NA, NB) { \
    int i1_ = ib + 1; if (i1_ == 3) i1_ = 0; \
    int i2_ = i1_ + 1; if (i2_ == 3) i2_ = 0; \
    if ((T) + 2 < NT) { \
        STAGE(i2_, (T)+2); \
        asm volatile("s_waitcnt vmcnt(3)" ::: "memory"); \
    } else if ((T) + 1 < NT) { \
        asm volatile("s_waitcnt vmcnt(0)" ::: "memory"); \
    } \
    fence_bar(); \
    __builtin_amdgcn_s_setprio(1); \
    if ((T) + 1 < NT) LDF2(i1_, NA, NB); \
    MM2(CA, CB); \
    __builtin_amdgcn_s_setprio(0); \
    asm volatile("s_waitcnt lgkmcnt(0)" ::: "memory"); \
    __builtin_amdgcn_sched_barrier(0); \
    ib = i1_; }

    for (int t = 0; t < NT; t += 2) {
        G2ITER(t,   a0, b0, a1, b1f);
        G2ITER(t+1, a1, b1f, a0, b0);
    }

    int lrow = (lane >> 4) * 4, lcol = lane & 15;
    #pragma unroll
    for (int n = 0; n < 4; n++) {
        int dcol = n0 + wc*64 + n*16 + lcol;
        float bias = bp[e*Dc + dcol];
        #pragma unroll
        for (int m = 0; m < 4; m++) {
            int rb2 = m0 + wr*64 + m*16 + lrow;
            #pragma unroll
            for (int j = 0; j < 4; j++) {
                int r = rb2 + j;
                if (r < n_e)
                    outb[(size_t)(base + r)*Dc + dcol] = acc[m][n][j] + bias;
            }
        }
    }
#undef G2ITER
#undef MM2
#undef LDF2
}

// ---------------- combine: final[t] = w0*OUT[s0] + w1*OUT[s1] ----------------
__global__ void k_combine(const float* __restrict__ outb, const int* __restrict__ slot_of,
                          const float* __restrict__ tok_w, float* __restrict__ final_out) {
    int gid = blockIdx.x * 256 + threadIdx.x;   // Tc*Dc/4 threads
    int t = gid >> 8;
    int c = (gid & 255) * 4;
    int s0 = slot_of[t*2], s1 = slot_of[t*2 + 1];
    float w0 = tok_w[t*2], w1 = tok_w[t*2 + 1];
    float4 o0 = *(const float4*)&outb[(size_t)s0*Dc + c];
    float4 o1 = *(const float4*)&outb[(size_t)s1*Dc + c];
    float4 r;
    r.x = w0*o0.x + w1*o1.x;
    r.y = w0*o0.y + w1*o1.y;
    r.z = w0*o0.z + w1*o1.z;
    r.w = w0*o0.w + w1*o1.w;
    *(float4*)&final_out[(size_t)t*Dc + c] = r;
}

extern "C" void kernel_launch(void* const* d_in, const int* in_sizes, int n_in,
                              void* d_out, int out_size, void* d_ws, size_t ws_size,
                              hipStream_t stream) {
    (void)in_sizes; (void)n_in; (void)out_size; (void)ws_size;
    const float* x     = (const float*)d_in[0];
    const float* noise = (const float*)d_in[1];
    const float* Wg    = (const float*)d_in[2];
    const float* nw    = (const float*)d_in[3];
    const float* W1    = (const float*)d_in[4];
    const float* b1    = (const float*)d_in[5];
    const float* W2    = (const float*)d_in[6];
    const float* b2    = (const float*)d_in[7];
    const float* Wp    = (const float*)d_in[8];
    const float* bp    = (const float*)d_in[9];

    char* ws = (char*)d_ws;
    size_t off = 0;
    unsigned short* W1P = (unsigned short*)(ws + off); off += (size_t)Ec*Dc*Hc*2;      // 64 MB
    unsigned short* W2P = (unsigned short*)(ws + off); off += (size_t)Ec*Dc*Hc*2;      // 64 MB
    unsigned short* WPP = (unsigned short*)(ws + off); off += (size_t)Ec*Hc*Dc*2;      // 64 MB
    unsigned short* APK = (unsigned short*)(ws + off); off += (size_t)32*PROWS*2;      // 16.5 MB
    unsigned short* HH2 = (unsigned short*)(ws + off); off += (size_t)128*PROWS*2;     // 66 MB
    float*          OUTB= (float*)(ws + off);          off += (size_t)NSLOT*Dc*4;      // 32 MB
    int*   counts    = (int*)(ws + off);
    int*   fill      = (int*)(ws + off + 32);
    int*   offsets   = (int*)(ws + off + 64);
    int*   tok_top   = (int*)(ws + off + 128);
    float* tok_w     = (float*)(ws + off + 128 + (size_t)Tc*2*4);
    int*   slot_token= (int*)(ws + off + 128 + (size_t)Tc*2*8);
    int*   slot_of   = (int*)(ws + off + 128 + (size_t)Tc*2*8 + (size_t)NSLOT*4);
    int*   slot_pos  = (int*)(ws + off + 128 + (size_t)Tc*2*8 + (size_t)NSLOT*8);

    float* final_out = (float*)d_out;
    float* idx_out   = (float*)d_out + FINAL_N;

    hipMemsetAsync(counts, 0, 64, stream);   // counts + fill

    // W1 + W2 panel transposes in one launch (z = 16: [0,8) -> W1, [8,16) -> W2)
    k_transpose_panel<<<dim3(Hc/64, Dc/64, 2*Ec), 256, 0, stream>>>(W1, W2, W1P, W2P, Dc, Hc, Ec);
    k_transpose_panel<<<dim3(Dc/64, Hc/64, Ec), 256, 0, stream>>>(Wp, Wp, WPP, WPP, Hc, Dc, Ec);

    k_gate<<<Tc, 64, 0, stream>>>(x, noise, Wg, nw, idx_out, counts, tok_top, tok_w);
    k_scan<<<1, 64, 0, stream>>>(counts, offsets);
    k_fill<<<Tc/256, 256, 0, stream>>>(tok_top, offsets, fill, slot_token, slot_of, slot_pos);
    k_packA<<<NSLOT/4, 256, 0, stream>>>(x, slot_token, slot_pos, APK);

    k_gemm1<<<dim3(Hc/BN1, Tc/BM1, Ec), 512, 0, stream>>>(APK, W1P, W2P, b1, b2,
                                                          counts, offsets, HH2);
    k_gemm2<<<dim3(Dc/BN2, Tc/BM2, Ec), 512, 0, stream>>>(HH2, WPP, bp, counts, offsets, OUTB);
    k_combine<<<(Tc*Dc/4)/256, 256, 0, stream>>>(OUTB, slot_of, tok_w, final_out);
}